// Round 20
// baseline (721.880 us; speedup 1.0000x reference)
//
#include <hip/hip_runtime.h>
#include <math.h>
#include <stddef.h>
#include <stdint.h>

// ---------------------------------------------------------------------------
// ReNet: patches -> vert bidir LSTM -> horiz bidir LSTM -> dense+relu
// B=64, I=J=32, D=12, HID=256, FC=1024.
// Round 20: gemms BK 64->128 (barriers 16->8, same load count, occupancy
// unchanged at 2 blocks/CU); s_setprio(1) around the sweep MFMA rings (wave
// role-drift regime). Sweep structure frozen (r19's sweepV + sweep7).
// ---------------------------------------------------------------------------

namespace {

typedef __bf16 bf16x8 __attribute__((ext_vector_type(8)));
typedef float f32x4 __attribute__((ext_vector_type(4)));
typedef __attribute__((address_space(1))) unsigned int as1_uint;
typedef __attribute__((address_space(3))) unsigned int as3_uint;

__device__ __forceinline__ float bf2f(ushort u) {
  return __builtin_bit_cast(float, (unsigned int)u << 16);
}
__device__ __forceinline__ ushort f2bf(float f) {
  unsigned int u = __builtin_bit_cast(unsigned int, f);
  u += 0x7fffu + ((u >> 16) & 1u);
  return (ushort)(u >> 16);
}
__device__ __forceinline__ float sigm(float x) {
  return __fdividef(1.f, 1.f + __expf(-x));
}
__device__ __forceinline__ float tanh_(float x) {
  return 2.f * sigm(2.f * x) - 1.f;
}
__device__ __forceinline__ f32x4 mfma16(bf16x8 a, bf16x8 b, f32x4 c) {
  return __builtin_amdgcn_mfma_f32_16x16x32_bf16(a, b, c, 0, 0, 0);
}
__device__ __forceinline__ void load_lds16(const void* g, void* l) {
  __builtin_amdgcn_global_load_lds((const as1_uint*)g, (as3_uint*)l, 16, 0, 0);
}

// Zf fragment-major layout, per (dir, rb16): 65536 uint4.
// index = ((seq*2 + q)*2 + p)*512 + tidz ; components = gates.
// uint packs bf16 local rows (2*n2l, 2*n2l+1), n2l = kg*2+p,
// tidz = w*64 + kg*16 + l16, hcol = w*32 + q*16 + l16.

// --------------------------------------------------------------------------
__global__ __launch_bounds__(256) void transpose_all(
    const float* __restrict__ s0, const float* __restrict__ s1,
    const float* __restrict__ s2, ushort* __restrict__ d0,
    ushort* __restrict__ d1, ushort* __restrict__ d2) {
  const int which = blockIdx.y;
  const float* in = (which == 0) ? s0 : (which == 1) ? s1 : s2;
  ushort* out = (which == 0) ? d0 : (which == 1) ? d1 : d2;
  const int idx = blockIdx.x * 256 + threadIdx.x;
  const int n = idx >> 9, k = idx & 511;
  out[idx] = f2bf(in[k * 1024 + n]);
}

// --------------------------------------------------------------------------
__global__ __launch_bounds__(256) void rfrag_all(
    const float* __restrict__ r0, const float* __restrict__ r1,
    const float* __restrict__ r2, const float* __restrict__ r3,
    ushort* __restrict__ out) {
  const int which = blockIdx.y;
  const float* r = (which == 0) ? r0 : (which == 1) ? r1 : (which == 2) ? r2 : r3;
  ushort* o = out + (size_t)which * 262144;
  const int id = blockIdx.x * 256 + threadIdx.x;
  const int lane = id & 63, kc = (id >> 6) & 7, tile = id >> 9;
  const int kbase = (kc << 5) + ((lane >> 4) << 3);
  const int col = (tile << 4) + (lane & 15);
  ushort tmp[8];
#pragma unroll
  for (int j = 0; j < 8; ++j) tmp[j] = f2bf(r[(size_t)(kbase + j) * 1024 + col]);
  *(uint4*)&o[(size_t)id << 3] = *(const uint4*)tmp;
}

// --------------------------------------------------------------------------
__global__ __launch_bounds__(256) void kfragv_kernel(
    const float* __restrict__ k0, const float* __restrict__ b0,
    const float* __restrict__ k1, const float* __restrict__ b1,
    ushort* __restrict__ out) {
  const int dir = blockIdx.y;
  const int idx = blockIdx.x * 256 + threadIdx.x;
  const int lane = idx & 63;
  const int kbase = (lane >> 4) << 3;
  const int col = ((idx >> 6) << 4) + (lane & 15);
  const float* kw = dir ? k1 : k0;
  const float* bw = dir ? b1 : b0;
  ushort tmp[8];
#pragma unroll
  for (int j = 0; j < 8; ++j) {
    const int kidx = kbase + j;
    const float v = (kidx < 12) ? kw[kidx * 1024 + col]
                  : (kidx == 12) ? bw[col] : 0.f;
    tmp[j] = f2bf(v);
  }
  *(uint4*)&out[((size_t)dir * 4096 + idx) << 3] = *(const uint4*)tmp;
}

// --------------------------------------------------------------------------
// VERTICAL LSTM sweep (r19 sweepV + setprio around MFMA).
__global__ __launch_bounds__(512) void lstm_sweepV(
    const float* __restrict__ x, const ushort* __restrict__ kfragV,
    const uint4* __restrict__ rF, ushort* __restrict__ outbuf) {
  const int tid = threadIdx.x;
  const int lane = tid & 63, w = tid >> 6;
  const int l16 = lane & 15, kg = lane >> 4;
  const int rb = blockIdx.x, dir = (int)blockIdx.y;
  const int rowbase = rb << 4;
  const int bb = rb >> 1;
  const int jbase = (rb & 1) << 4;

  __shared__ ushort hbuf[2][4096];
  __shared__ uint4 kfr[4096];
  __shared__ ushort pb[2][512];

  const uint4* rFd = rF + (size_t)dir * 32768;

  for (int e = tid; e < 640; e += 512) {
    const int par = e / 320, rest = e - par * 320;
    const int row = rest / 20, c = 12 + rest % 20;
    pb[par][(row << 5) + c] = (c == 12) ? (ushort)0x3F80 : (ushort)0;
  }
  if (tid < 192) {
    const int row = tid / 12, d = tid - row * 12;
    const int pr = d / 6, rem = d - pr * 6, pc = rem / 3, c = rem - pc * 3;
    const int i0 = dir ? 31 : 0;
    const float v = x[((size_t)((bb * 64 + (i0 << 1) + pr) * 64) +
                       ((jbase + row) << 1) + pc) * 3 + c];
    pb[0][(row << 5) + d] = f2bf(v);
  }
#pragma unroll
  for (int i = 0; i < 8; ++i)
    load_lds16((const uint4*)kfragV + (size_t)dir * 4096 + tid + (i << 9),
               kfr + (tid - lane) + (i << 9));
  __syncthreads();

  float cst[2][4];
#pragma unroll
  for (int q = 0; q < 2; ++q)
#pragma unroll
    for (int r = 0; r < 4; ++r) cst[q][r] = 0.f;

  for (int t = 0; t < 32; ++t) {
    const ushort* hprev = hbuf[(t + 1) & 1];
    ushort* hnext = hbuf[t & 1];

    if (t) {
      const int seqP = dir ? (32 - t) : (t - 1);
      const int row = tid >> 5, c4o = tid & 31;
      const uint4 v = *(const uint4*)((const char*)hprev + row * 512 +
                                      ((c4o ^ (row & 7)) << 4));
      const int n = rowbase + row, b = n >> 5, sp = n & 31;
      *(uint4*)&outbuf[(((size_t)(b * 32 + seqP) * 32 + sp) << 9) +
                       (dir << 8) + (c4o << 3)] = v;
    }

    float pv = 0.f;
    if (t < 31 && tid < 192) {
      const int row = tid / 12, d = tid - row * 12;
      const int pr = d / 6, rem = d - pr * 6, pc = rem / 3, c = rem - pc * 3;
      const int iN = dir ? (30 - t) : (t + 1);
      pv = x[((size_t)((bb * 64 + (iN << 1) + pr) * 64) +
              ((jbase + row) << 1) + pc) * 3 + c];
    }

    const bf16x8 pf = __builtin_bit_cast(
        bf16x8, *(const uint4*)&pb[t & 1][(l16 << 5) + (kg << 3)]);
    f32x4 acc[2][4];
#pragma unroll
    for (int q = 0; q < 2; ++q) {
#pragma unroll
      for (int g = 0; g < 4; ++g) {
        const int tile = (g << 4) + (w << 1) + q;
        const bf16x8 kb = __builtin_bit_cast(bf16x8, kfr[(tile << 6) + lane]);
        acc[q][g] = mfma16(pf, kb, (f32x4){0.f, 0.f, 0.f, 0.f});
      }
    }

    if (t) {
      __builtin_amdgcn_s_setprio(1);
#pragma unroll
      for (int q = 0; q < 2; ++q) {
        uint4 bfr[2][4];
#pragma unroll
        for (int g = 0; g < 4; ++g)
          bfr[0][g] = rFd[(size_t)(((g << 4) + (w << 1) + q) << 3) * 64 + lane];
#pragma unroll
        for (int kc = 0; kc < 8; ++kc) {
          const int cur = kc & 1;
          if (kc < 7) {
#pragma unroll
            for (int g = 0; g < 4; ++g)
              bfr[cur ^ 1][g] =
                  rFd[((size_t)(((g << 4) + (w << 1) + q) << 3) + kc + 1) * 64 +
                      lane];
          }
          const int c4 = (kc << 2) + kg;
          const uint4 a = *(const uint4*)((const char*)hprev + l16 * 512 +
                                          ((c4 ^ (l16 & 7)) << 4));
          const bf16x8 ab = __builtin_bit_cast(bf16x8, a);
#pragma unroll
          for (int g = 0; g < 4; ++g)
            acc[q][g] =
                mfma16(ab, __builtin_bit_cast(bf16x8, bfr[cur][g]), acc[q][g]);
        }
      }
      __builtin_amdgcn_s_setprio(0);
    }

    if (t < 31 && tid < 192) {
      const int row = tid / 12, d = tid - row * 12;
      pb[(t + 1) & 1][(row << 5) + d] = f2bf(pv);
    }

#pragma unroll
    for (int q = 0; q < 2; ++q) {
      const int col = (w << 5) + (q << 4) + l16;
#pragma unroll
      for (int r = 0; r < 4; ++r) {
        const float zi = acc[q][0][r];
        const float zf = acc[q][1][r];
        const float zg = acc[q][2][r];
        const float zo = acc[q][3][r];
        const float cn = sigm(zf) * cst[q][r] + sigm(zi) * tanh_(zg);
        cst[q][r] = cn;
        const float hv = sigm(zo) * tanh_(cn);
        const int row = (kg << 2) + r;
        *(ushort*)((char*)hnext + row * 512 +
                   (((col >> 3) ^ (row & 7)) << 4) + ((col & 7) << 1)) =
            f2bf(hv);
      }
    }
    __syncthreads();
  }

  {
    const int seqP = dir ? 0 : 31;
    const ushort* hl = hbuf[1];
    const int row = tid >> 5, c4o = tid & 31;
    const uint4 v = *(const uint4*)((const char*)hl + row * 512 +
                                    ((c4o ^ (row & 7)) << 4));
    const int n = rowbase + row, b = n >> 5, sp = n & 31;
    *(uint4*)&outbuf[(((size_t)(b * 32 + seqP) * 32 + sp) << 9) + (dir << 8) +
                     (c4o << 3)] = v;
  }
}

// --------------------------------------------------------------------------
// HORIZONTAL LSTM sweep (sweep7 + setprio around MFMA).
__global__ __launch_bounds__(512) void lstm_sweep7(
    const uint4* __restrict__ Zf, const uint4* __restrict__ rF,
    ushort* __restrict__ outbuf, int vert) {
  const int tid = threadIdx.x;
  const int lane = tid & 63, w = tid >> 6;
  const int l16 = lane & 15, kg = lane >> 4;
  const int rb = blockIdx.x, dir = (int)blockIdx.y;
  const int rowbase = rb << 4;

  __shared__ ushort hbuf[2][4096];

  const uint4* rFd = rF + (size_t)dir * 32768;
  const uint4* zb = Zf + ((size_t)dir * 128 + rb) * 65536;

  float cst[2][4];
#pragma unroll
  for (int q = 0; q < 2; ++q)
#pragma unroll
    for (int r = 0; r < 4; ++r) cst[q][r] = 0.f;

  uint4 zA[2], zB[2];
  {
    const int seq0 = dir ? 31 : 0;
    zA[0] = zb[(size_t)(seq0 << 2) * 512 + tid];
    zA[1] = zb[(size_t)((seq0 << 2) + 1) * 512 + tid];
  }

  for (int t = 0; t < 32; ++t) {
    const ushort* hprev = hbuf[(t + 1) & 1];
    ushort* hnext = hbuf[t & 1];

    if (t) {
      const int seqP = dir ? (32 - t) : (t - 1);
      const int row = tid >> 5, c4 = tid & 31;
      const uint4 v = *(const uint4*)((const char*)hprev + row * 512 +
                                      ((c4 ^ (row & 7)) << 4));
      const int n = rowbase + row, b = n >> 5, sp = n & 31;
      const int X = vert ? seqP : sp, Y = vert ? sp : seqP;
      *(uint4*)&outbuf[(((size_t)(b * 32 + X) * 32 + Y) << 9) + (dir << 8) +
                       (c4 << 3)] = v;
    }

#pragma unroll
    for (int q = 0; q < 2; ++q) {
      uint4(&zc)[2] = (q == 0) ? zA : zB;
      uint4(&zn)[2] = (q == 0) ? zB : zA;

      f32x4 acc[4];
#pragma unroll
      for (int g = 0; g < 4; ++g) {
        const unsigned int u0 = (g == 0) ? zc[0].x : (g == 1) ? zc[0].y
                                : (g == 2) ? zc[0].z : zc[0].w;
        const unsigned int u1 = (g == 0) ? zc[1].x : (g == 1) ? zc[1].y
                                : (g == 2) ? zc[1].z : zc[1].w;
        acc[g][0] = bf2f((ushort)(u0 & 0xffffu));
        acc[g][1] = bf2f((ushort)(u0 >> 16));
        acc[g][2] = bf2f((ushort)(u1 & 0xffffu));
        acc[g][3] = bf2f((ushort)(u1 >> 16));
      }

      if (t) {
        __builtin_amdgcn_s_setprio(1);
        uint4 bfr[2][4];
#pragma unroll
        for (int g = 0; g < 4; ++g)
          bfr[0][g] = rFd[(size_t)(((g << 4) + (w << 1) + q) << 3) * 64 + lane];
#pragma unroll
        for (int kc = 0; kc < 8; ++kc) {
          const int cur = kc & 1;
          if (kc < 7) {
#pragma unroll
            for (int g = 0; g < 4; ++g)
              bfr[cur ^ 1][g] =
                  rFd[((size_t)(((g << 4) + (w << 1) + q) << 3) + kc + 1) * 64 +
                      lane];
          }
          const int c4 = (kc << 2) + kg;
          const uint4 a = *(const uint4*)((const char*)hprev + l16 * 512 +
                                          ((c4 ^ (l16 & 7)) << 4));
          const bf16x8 ab = __builtin_bit_cast(bf16x8, a);
#pragma unroll
          for (int g = 0; g < 4; ++g)
            acc[g] = mfma16(ab, __builtin_bit_cast(bf16x8, bfr[cur][g]), acc[g]);
        }
        __builtin_amdgcn_s_setprio(0);
      }

      if (t < 31 || q == 0) {
        const int tn = q ? (t + 1) : t;
        const int qn = q ^ 1;
        const int seqn = dir ? (31 - tn) : tn;
        zn[0] = zb[(size_t)(((seqn << 1) + qn) << 1) * 512 + tid];
        zn[1] = zb[(size_t)((((seqn << 1) + qn) << 1) + 1) * 512 + tid];
      }

      const int col = (w << 5) + (q << 4) + l16;
#pragma unroll
      for (int r = 0; r < 4; ++r) {
        const float zi = acc[0][r];
        const float zf = acc[1][r];
        const float zg = acc[2][r];
        const float zo = acc[3][r];
        const float cn = sigm(zf) * cst[q][r] + sigm(zi) * tanh_(zg);
        cst[q][r] = cn;
        const float hv = sigm(zo) * tanh_(cn);
        const int row = (kg << 2) + r;
        *(ushort*)((char*)hnext + row * 512 +
                   (((col >> 3) ^ (row & 7)) << 4) + ((col & 7) << 1)) =
            f2bf(hv);
      }
    }
    __syncthreads();
  }

  {
    const int seqP = dir ? 0 : 31;
    const ushort* hl = hbuf[1];
    const int row = tid >> 5, c4 = tid & 31;
    const uint4 v = *(const uint4*)((const char*)hl + row * 512 +
                                    ((c4 ^ (row & 7)) << 4));
    const int n = rowbase + row, b = n >> 5, sp = n & 31;
    const int X = vert ? seqP : sp, Y = vert ? sp : seqP;
    *(uint4*)&outbuf[(((size_t)(b * 32 + X) * 32 + Y) << 9) + (dir << 8) +
                     (c4 << 3)] = v;
  }
}

// --------------------------------------------------------------------------
// Dual-dir horizontal projection, 8-wave blocks, BK=128 (4 K-iters, 8 barriers).
__global__ __launch_bounds__(512) void gemm_bt_dual(
    const ushort* __restrict__ A, const ushort* __restrict__ BT0,
    const ushort* __restrict__ BT1, const float* __restrict__ bias0,
    const float* __restrict__ bias1, uint4* __restrict__ Zf) {
  const int tid = threadIdx.x;
  const int lane = tid & 63, wid = tid >> 6;
  const int l16 = lane & 15, kg = lane >> 4;
  const int wr = wid >> 1, wc = wid & 1;  // 4m x 2n
  const int bid = blockIdx.x;
  const int xcd = bid & 7, lid = bid >> 3;
  const int m0 = ((xcd << 6) + (lid >> 4)) << 7;
  const int nb = lid & 15;
  const int dirq = nb >> 3;
  const int hc0 = (nb & 7) << 5;
  const ushort* BT = dirq ? BT1 : BT0;
  const float* bias = dirq ? bias1 : bias0;
  uint4* Cz = Zf + (size_t)dirq * 8388608;

  union SM {
    struct { uint4 A[128][16]; uint4 B[128][16]; } k;  // 64 KB
    ushort eh[128][136];
  };
  __shared__ SM sm;

  f32x4 acc[2][4];
#pragma unroll
  for (int mt = 0; mt < 2; ++mt)
#pragma unroll
    for (int nt = 0; nt < 4; ++nt) acc[mt][nt] = (f32x4){0.f, 0.f, 0.f, 0.f};

  for (int k0 = 0; k0 < 512; k0 += 128) {
#pragma unroll
    for (int c = 0; c < 4; ++c) {
      const int cid = (wid << 8) + (c << 6) + lane;  // 0..2047
      const int row = cid >> 4, ch = cid & 15;
      const int sch = ch ^ (row & 7);
      const int brow = ((row >> 5) << 8) + hc0 + (row & 31);
      load_lds16(A + (size_t)(m0 + row) * 512 + k0 + (sch << 3),
                 (uint4*)sm.k.A + (cid - lane));
      load_lds16(BT + (size_t)brow * 512 + k0 + (sch << 3),
                 (uint4*)sm.k.B + (cid - lane));
    }
    __syncthreads();
#pragma unroll
    for (int kk = 0; kk < 4; ++kk) {
      const int q = (kk << 2) + kg;
      bf16x8 a[2], b[4];
#pragma unroll
      for (int mt = 0; mt < 2; ++mt) {
        const int rr = (wr << 5) + (mt << 4) + l16;
        a[mt] = __builtin_bit_cast(bf16x8, sm.k.A[rr][q ^ (rr & 7)]);
      }
#pragma unroll
      for (int nt = 0; nt < 4; ++nt) {
        const int rr = (wc << 6) + (nt << 4) + l16;
        b[nt] = __builtin_bit_cast(bf16x8, sm.k.B[rr][q ^ (rr & 7)]);
      }
#pragma unroll
      for (int mt = 0; mt < 2; ++mt)
#pragma unroll
        for (int nt = 0; nt < 4; ++nt)
          acc[mt][nt] = mfma16(a[mt], b[nt], acc[mt][nt]);
    }
    __syncthreads();
  }

  float bn[4];
#pragma unroll
  for (int nt = 0; nt < 4; ++nt) {
    const int lcol = (wc << 6) + (nt << 4) + l16;
    bn[nt] = bias[((lcol >> 5) << 8) + hc0 + (lcol & 31)];
  }

#pragma unroll
  for (int mt = 0; mt < 2; ++mt) {
#pragma unroll
    for (int nt = 0; nt < 4; ++nt) {
      const int col = (wc << 6) + (nt << 4) + l16;
#pragma unroll
      for (int r = 0; r < 4; ++r) {
        const int rowl = (wr << 5) + (mt << 4) + (kg << 2) + r;
        sm.eh[rowl][col] = f2bf(acc[mt][nt][r] + bn[nt]);
      }
    }
  }
  __syncthreads();

#pragma unroll
  for (int h = 0; h < 2; ++h) {
    const int n_a = ((m0 >> 6) + h) << 1;
    const int rbz = n_a >> 4;
    const int n2l = (n_a & 15) >> 1;
    const int kgz = n2l >> 1, pz = n2l & 1;
#pragma unroll
    for (int it = 0; it < 2; ++it) {
      const int e = tid + (it << 9);
      const int seq = e >> 5, hl = e & 31;
      const int qv = hl >> 4, l16v = hl & 15;
      const int wz = (hc0 + hl) >> 5;
      const int tidz = (wz << 6) + (kgz << 4) + l16v;
      uint4 o;
      o.x = (unsigned int)sm.eh[(h << 6) + seq][hl] |
            ((unsigned int)sm.eh[(h << 6) + 32 + seq][hl] << 16);
      o.y = (unsigned int)sm.eh[(h << 6) + seq][32 + hl] |
            ((unsigned int)sm.eh[(h << 6) + 32 + seq][32 + hl] << 16);
      o.z = (unsigned int)sm.eh[(h << 6) + seq][64 + hl] |
            ((unsigned int)sm.eh[(h << 6) + 32 + seq][64 + hl] << 16);
      o.w = (unsigned int)sm.eh[(h << 6) + seq][96 + hl] |
            ((unsigned int)sm.eh[(h << 6) + 32 + seq][96 + hl] << 16);
      Cz[(size_t)rbz * 65536 + (size_t)((((seq << 1) + qv) << 1) + pz) * 512 +
         tidz] = o;
    }
  }
}

// --------------------------------------------------------------------------
// Dense, 8-wave blocks, BK=128: out = relu(A @ WdT^T + bd), f32 stores.
__global__ __launch_bounds__(512) void gemm_dense(
    const ushort* __restrict__ A, const ushort* __restrict__ BT,
    const float* __restrict__ bias, float* __restrict__ out) {
  const int tid = threadIdx.x;
  const int lane = tid & 63, wid = tid >> 6;
  const int l16 = lane & 15, kg = lane >> 4;
  const int wr = wid >> 1, wc = wid & 1;
  const int bid = blockIdx.x;
  const int xcd = bid & 7, lid = bid >> 3;
  const int m0 = ((xcd << 6) + (lid >> 3)) << 7;
  const int n0 = (lid & 7) << 7;

  union SM {
    struct { uint4 A[128][16]; uint4 B[128][16]; } k;  // 64 KB
    float ef[64][132];
  };
  __shared__ SM sm;

  f32x4 acc[2][4];
#pragma unroll
  for (int mt = 0; mt < 2; ++mt)
#pragma unroll
    for (int nt = 0; nt < 4; ++nt) acc[mt][nt] = (f32x4){0.f, 0.f, 0.f, 0.f};

  for (int k0 = 0; k0 < 512; k0 += 128) {
#pragma unroll
    for (int c = 0; c < 4; ++c) {
      const int cid = (wid << 8) + (c << 6) + lane;  // 0..2047
      const int row = cid >> 4, ch = cid & 15;
      const int sch = ch ^ (row & 7);
      load_lds16(A + (size_t)(m0 + row) * 512 + k0 + (sch << 3),
                 (uint4*)sm.k.A + (cid - lane));
      load_lds16(BT + (size_t)(n0 + row) * 512 + k0 + (sch << 3),
                 (uint4*)sm.k.B + (cid - lane));
    }
    __syncthreads();
#pragma unroll
    for (int kk = 0; kk < 4; ++kk) {
      const int q = (kk << 2) + kg;
      bf16x8 a[2], b[4];
#pragma unroll
      for (int mt = 0; mt < 2; ++mt) {
        const int rr = (wr << 5) + (mt << 4) + l16;
        a[mt] = __builtin_bit_cast(bf16x8, sm.k.A[rr][q ^ (rr & 7)]);
      }
#pragma unroll
      for (int nt = 0; nt < 4; ++nt) {
        const int rr = (wc << 6) + (nt << 4) + l16;
        b[nt] = __builtin_bit_cast(bf16x8, sm.k.B[rr][q ^ (rr & 7)]);
      }
#pragma unroll
      for (int mt = 0; mt < 2; ++mt)
#pragma unroll
        for (int nt = 0; nt < 4; ++nt)
          acc[mt][nt] = mfma16(a[mt], b[nt], acc[mt][nt]);
    }
    __syncthreads();
  }

  float bn[4];
#pragma unroll
  for (int nt = 0; nt < 4; ++nt)
    bn[nt] = bias[n0 + (wc << 6) + (nt << 4) + l16];

#pragma unroll
  for (int h = 0; h < 2; ++h) {
    __syncthreads();
    if ((wr >> 1) == h) {
#pragma unroll
      for (int mt = 0; mt < 2; ++mt) {
#pragma unroll
        for (int nt = 0; nt < 4; ++nt) {
          const int col = (wc << 6) + (nt << 4) + l16;
#pragma unroll
          for (int r = 0; r < 4; ++r) {
            const int rowl = ((wr & 1) << 5) + (mt << 4) + (kg << 2) + r;
            sm.ef[rowl][col] = fmaxf(acc[mt][nt][r] + bn[nt], 0.f);
          }
        }
      }
    }
    __syncthreads();
#pragma unroll
    for (int it = 0; it < 4; ++it) {
      const int c = tid + (it << 9);
      const int row = c >> 5, co = (c & 31) << 2;
      const f32x4 v = *(const f32x4*)&sm.ef[row][co];
      __builtin_nontemporal_store(
          v, (f32x4*)(out + (size_t)(m0 + (h << 6) + row) * 1024 + n0 + co));
    }
  }
}

}  // namespace

extern "C" void kernel_launch(void* const* d_in, const int* in_sizes, int n_in,
                              void* d_out, int out_size, void* d_ws, size_t ws_size,
                              hipStream_t stream) {
  (void)in_sizes; (void)n_in; (void)out_size; (void)ws_size;
  const float* x    = (const float*)d_in[0];
  const float* k_ud = (const float*)d_in[1];
  const float* r_ud = (const float*)d_in[2];
  const float* b_ud = (const float*)d_in[3];
  const float* k_du = (const float*)d_in[4];
  const float* r_du = (const float*)d_in[5];
  const float* b_du = (const float*)d_in[6];
  const float* k_lr = (const float*)d_in[7];
  const float* r_lr = (const float*)d_in[8];
  const float* b_lr = (const float*)d_in[9];
  const float* k_rl = (const float*)d_in[10];
  const float* r_rl = (const float*)d_in[11];
  const float* b_rl = (const float*)d_in[12];
  const float* Wd   = (const float*)d_in[13];
  const float* bd   = (const float*)d_in[14];

  ushort* W     = (ushort*)d_ws;
  ushort* Z     = W;                      // Zf: 268 MB
  ushort* vbuf  = Z + 134217728;          // 33554432
  ushort* rF    = vbuf + 33554432;        // 1048576
  ushort* kTh   = rF + 1048576;           // 1048576
  ushort* WdT   = kTh + 1048576;          // 524288
  ushort* kfragV = WdT + 524288;          // 65536
  uint4* Zf = (uint4*)Z;

  // ---- weight prep ----
  rfrag_all<<<dim3(128, 4), 256, 0, stream>>>(r_ud, r_du, r_lr, r_rl, rF);
  transpose_all<<<dim3(2048, 3), 256, 0, stream>>>(k_lr, k_rl, Wd, kTh,
                                                   kTh + 524288, WdT);
  kfragv_kernel<<<dim3(16, 2), 256, 0, stream>>>(k_ud, b_ud, k_du, b_du,
                                                 kfragV);

  // ---- vertical sweep (zx in-kernel) ----
  lstm_sweepV<<<dim3(128, 2), 512, 0, stream>>>(x, kfragV, (const uint4*)rF,
                                                vbuf);

  // ---- horizontal input projection (both dirs, BK=128) ----
  gemm_bt_dual<<<8192, 512, 0, stream>>>(vbuf, kTh, kTh + 524288, b_lr, b_rl,
                                         Zf);

  // ---- horizontal sweep ----
  lstm_sweep7<<<dim3(128, 2), 512, 0, stream>>>(
      Zf, (const uint4*)(rF + 524288), vbuf, 0);

  // ---- dense + relu (BK=128) ----
  gemm_dense<<<4096, 512, 0, stream>>>(vbuf, WdT, bd, (float*)d_out);
}

// Round 21
// 694.022 us; speedup vs baseline: 1.0401x; 1.0401x over previous
//
#include <hip/hip_runtime.h>
#include <math.h>
#include <stddef.h>
#include <stdint.h>

// ---------------------------------------------------------------------------
// ReNet: patches -> vert bidir LSTM -> horiz bidir LSTM -> dense+relu
// B=64, I=J=32, D=12, HID=256, FC=1024.
// Round 21: (a) sweep7: gate-0 R panel (128KB) LDS-resident -> per-step L2
// stream 512->384 KB (sweep is ~50% L2-BW-bound); (b) gemms: double-buffered
// LDS staging, stage(t+1) issued before MFMA(t), one __syncthreads/iter.
// r20's null levers (setprio, BK=128) reverted. sweepV = control (r19 body).
// ---------------------------------------------------------------------------

namespace {

typedef __bf16 bf16x8 __attribute__((ext_vector_type(8)));
typedef float f32x4 __attribute__((ext_vector_type(4)));
typedef __attribute__((address_space(1))) unsigned int as1_uint;
typedef __attribute__((address_space(3))) unsigned int as3_uint;

__device__ __forceinline__ float bf2f(ushort u) {
  return __builtin_bit_cast(float, (unsigned int)u << 16);
}
__device__ __forceinline__ ushort f2bf(float f) {
  unsigned int u = __builtin_bit_cast(unsigned int, f);
  u += 0x7fffu + ((u >> 16) & 1u);
  return (ushort)(u >> 16);
}
__device__ __forceinline__ float sigm(float x) {
  return __fdividef(1.f, 1.f + __expf(-x));
}
__device__ __forceinline__ float tanh_(float x) {
  return 2.f * sigm(2.f * x) - 1.f;
}
__device__ __forceinline__ f32x4 mfma16(bf16x8 a, bf16x8 b, f32x4 c) {
  return __builtin_amdgcn_mfma_f32_16x16x32_bf16(a, b, c, 0, 0, 0);
}
__device__ __forceinline__ void load_lds16(const void* g, void* l) {
  __builtin_amdgcn_global_load_lds((const as1_uint*)g, (as3_uint*)l, 16, 0, 0);
}

// Zf fragment-major layout, per (dir, rb16): 65536 uint4.
// index = ((seq*2 + q)*2 + p)*512 + tidz ; components = gates.
// uint packs bf16 local rows (2*n2l, 2*n2l+1), n2l = kg*2+p,
// tidz = w*64 + kg*16 + l16, hcol = w*32 + q*16 + l16.

// --------------------------------------------------------------------------
__global__ __launch_bounds__(256) void transpose_all(
    const float* __restrict__ s0, const float* __restrict__ s1,
    const float* __restrict__ s2, ushort* __restrict__ d0,
    ushort* __restrict__ d1, ushort* __restrict__ d2) {
  const int which = blockIdx.y;
  const float* in = (which == 0) ? s0 : (which == 1) ? s1 : s2;
  ushort* out = (which == 0) ? d0 : (which == 1) ? d1 : d2;
  const int idx = blockIdx.x * 256 + threadIdx.x;
  const int n = idx >> 9, k = idx & 511;
  out[idx] = f2bf(in[k * 1024 + n]);
}

// --------------------------------------------------------------------------
__global__ __launch_bounds__(256) void rfrag_all(
    const float* __restrict__ r0, const float* __restrict__ r1,
    const float* __restrict__ r2, const float* __restrict__ r3,
    ushort* __restrict__ out) {
  const int which = blockIdx.y;
  const float* r = (which == 0) ? r0 : (which == 1) ? r1 : (which == 2) ? r2 : r3;
  ushort* o = out + (size_t)which * 262144;
  const int id = blockIdx.x * 256 + threadIdx.x;
  const int lane = id & 63, kc = (id >> 6) & 7, tile = id >> 9;
  const int kbase = (kc << 5) + ((lane >> 4) << 3);
  const int col = (tile << 4) + (lane & 15);
  ushort tmp[8];
#pragma unroll
  for (int j = 0; j < 8; ++j) tmp[j] = f2bf(r[(size_t)(kbase + j) * 1024 + col]);
  *(uint4*)&o[(size_t)id << 3] = *(const uint4*)tmp;
}

// --------------------------------------------------------------------------
__global__ __launch_bounds__(256) void kfragv_kernel(
    const float* __restrict__ k0, const float* __restrict__ b0,
    const float* __restrict__ k1, const float* __restrict__ b1,
    ushort* __restrict__ out) {
  const int dir = blockIdx.y;
  const int idx = blockIdx.x * 256 + threadIdx.x;
  const int lane = idx & 63;
  const int kbase = (lane >> 4) << 3;
  const int col = ((idx >> 6) << 4) + (lane & 15);
  const float* kw = dir ? k1 : k0;
  const float* bw = dir ? b1 : b0;
  ushort tmp[8];
#pragma unroll
  for (int j = 0; j < 8; ++j) {
    const int kidx = kbase + j;
    const float v = (kidx < 12) ? kw[kidx * 1024 + col]
                  : (kidx == 12) ? bw[col] : 0.f;
    tmp[j] = f2bf(v);
  }
  *(uint4*)&out[((size_t)dir * 4096 + idx) << 3] = *(const uint4*)tmp;
}

// --------------------------------------------------------------------------
// VERTICAL LSTM sweep (r19 body, control -- no changes).
__global__ __launch_bounds__(512) void lstm_sweepV(
    const float* __restrict__ x, const ushort* __restrict__ kfragV,
    const uint4* __restrict__ rF, ushort* __restrict__ outbuf) {
  const int tid = threadIdx.x;
  const int lane = tid & 63, w = tid >> 6;
  const int l16 = lane & 15, kg = lane >> 4;
  const int rb = blockIdx.x, dir = (int)blockIdx.y;
  const int rowbase = rb << 4;
  const int bb = rb >> 1;
  const int jbase = (rb & 1) << 4;

  __shared__ ushort hbuf[2][4096];
  __shared__ uint4 kfr[4096];
  __shared__ ushort pb[2][512];

  const uint4* rFd = rF + (size_t)dir * 32768;

  for (int e = tid; e < 640; e += 512) {
    const int par = e / 320, rest = e - par * 320;
    const int row = rest / 20, c = 12 + rest % 20;
    pb[par][(row << 5) + c] = (c == 12) ? (ushort)0x3F80 : (ushort)0;
  }
  if (tid < 192) {
    const int row = tid / 12, d = tid - row * 12;
    const int pr = d / 6, rem = d - pr * 6, pc = rem / 3, c = rem - pc * 3;
    const int i0 = dir ? 31 : 0;
    const float v = x[((size_t)((bb * 64 + (i0 << 1) + pr) * 64) +
                       ((jbase + row) << 1) + pc) * 3 + c];
    pb[0][(row << 5) + d] = f2bf(v);
  }
#pragma unroll
  for (int i = 0; i < 8; ++i)
    load_lds16((const uint4*)kfragV + (size_t)dir * 4096 + tid + (i << 9),
               kfr + (tid - lane) + (i << 9));
  __syncthreads();

  float cst[2][4];
#pragma unroll
  for (int q = 0; q < 2; ++q)
#pragma unroll
    for (int r = 0; r < 4; ++r) cst[q][r] = 0.f;

  for (int t = 0; t < 32; ++t) {
    const ushort* hprev = hbuf[(t + 1) & 1];
    ushort* hnext = hbuf[t & 1];

    if (t) {
      const int seqP = dir ? (32 - t) : (t - 1);
      const int row = tid >> 5, c4o = tid & 31;
      const uint4 v = *(const uint4*)((const char*)hprev + row * 512 +
                                      ((c4o ^ (row & 7)) << 4));
      const int n = rowbase + row, b = n >> 5, sp = n & 31;
      *(uint4*)&outbuf[(((size_t)(b * 32 + seqP) * 32 + sp) << 9) +
                       (dir << 8) + (c4o << 3)] = v;
    }

    float pv = 0.f;
    if (t < 31 && tid < 192) {
      const int row = tid / 12, d = tid - row * 12;
      const int pr = d / 6, rem = d - pr * 6, pc = rem / 3, c = rem - pc * 3;
      const int iN = dir ? (30 - t) : (t + 1);
      pv = x[((size_t)((bb * 64 + (iN << 1) + pr) * 64) +
              ((jbase + row) << 1) + pc) * 3 + c];
    }

    const bf16x8 pf = __builtin_bit_cast(
        bf16x8, *(const uint4*)&pb[t & 1][(l16 << 5) + (kg << 3)]);
    f32x4 acc[2][4];
#pragma unroll
    for (int q = 0; q < 2; ++q) {
#pragma unroll
      for (int g = 0; g < 4; ++g) {
        const int tile = (g << 4) + (w << 1) + q;
        const bf16x8 kb = __builtin_bit_cast(bf16x8, kfr[(tile << 6) + lane]);
        acc[q][g] = mfma16(pf, kb, (f32x4){0.f, 0.f, 0.f, 0.f});
      }
    }

    if (t) {
#pragma unroll
      for (int q = 0; q < 2; ++q) {
        uint4 bfr[2][4];
#pragma unroll
        for (int g = 0; g < 4; ++g)
          bfr[0][g] = rFd[(size_t)(((g << 4) + (w << 1) + q) << 3) * 64 + lane];
#pragma unroll
        for (int kc = 0; kc < 8; ++kc) {
          const int cur = kc & 1;
          if (kc < 7) {
#pragma unroll
            for (int g = 0; g < 4; ++g)
              bfr[cur ^ 1][g] =
                  rFd[((size_t)(((g << 4) + (w << 1) + q) << 3) + kc + 1) * 64 +
                      lane];
          }
          const int c4 = (kc << 2) + kg;
          const uint4 a = *(const uint4*)((const char*)hprev + l16 * 512 +
                                          ((c4 ^ (l16 & 7)) << 4));
          const bf16x8 ab = __builtin_bit_cast(bf16x8, a);
#pragma unroll
          for (int g = 0; g < 4; ++g)
            acc[q][g] =
                mfma16(ab, __builtin_bit_cast(bf16x8, bfr[cur][g]), acc[q][g]);
        }
      }
    }

    if (t < 31 && tid < 192) {
      const int row = tid / 12, d = tid - row * 12;
      pb[(t + 1) & 1][(row << 5) + d] = f2bf(pv);
    }

#pragma unroll
    for (int q = 0; q < 2; ++q) {
      const int col = (w << 5) + (q << 4) + l16;
#pragma unroll
      for (int r = 0; r < 4; ++r) {
        const float zi = acc[q][0][r];
        const float zf = acc[q][1][r];
        const float zg = acc[q][2][r];
        const float zo = acc[q][3][r];
        const float cn = sigm(zf) * cst[q][r] + sigm(zi) * tanh_(zg);
        cst[q][r] = cn;
        const float hv = sigm(zo) * tanh_(cn);
        const int row = (kg << 2) + r;
        *(ushort*)((char*)hnext + row * 512 +
                   (((col >> 3) ^ (row & 7)) << 4) + ((col & 7) << 1)) =
            f2bf(hv);
      }
    }
    __syncthreads();
  }

  {
    const int seqP = dir ? 0 : 31;
    const ushort* hl = hbuf[1];
    const int row = tid >> 5, c4o = tid & 31;
    const uint4 v = *(const uint4*)((const char*)hl + row * 512 +
                                    ((c4o ^ (row & 7)) << 4));
    const int n = rowbase + row, b = n >> 5, sp = n & 31;
    *(uint4*)&outbuf[(((size_t)(b * 32 + seqP) * 32 + sp) << 9) + (dir << 8) +
                     (c4o << 3)] = v;
  }
}

// --------------------------------------------------------------------------
// HORIZONTAL LSTM sweep: sweep7 + gate-0 R panel LDS-resident (128 KB).
// Per-step L2 stream drops 512 -> 384 KB. bfr ring covers g=1..3 only.
__global__ __launch_bounds__(512) void lstm_sweep7(
    const uint4* __restrict__ Zf, const uint4* __restrict__ rF,
    ushort* __restrict__ outbuf, int vert) {
  const int tid = threadIdx.x;
  const int lane = tid & 63, w = tid >> 6;
  const int l16 = lane & 15, kg = lane >> 4;
  const int rb = blockIdx.x, dir = (int)blockIdx.y;
  const int rowbase = rb << 4;

  __shared__ ushort hbuf[2][4096];  // 16 KB
  __shared__ uint4 rres[8192];      // 128 KB: g=0 tiles 0..15, all kc

  const uint4* rFd = rF + (size_t)dir * 32768;
  const uint4* zb = Zf + ((size_t)dir * 128 + rb) * 65536;

  // stage gate-0 R panel once (linear 128 KB); drained by step-0 barrier
#pragma unroll
  for (int i = 0; i < 16; ++i)
    load_lds16(rFd + (i << 9) + tid, rres + (tid - lane) + (i << 9));

  float cst[2][4];
#pragma unroll
  for (int q = 0; q < 2; ++q)
#pragma unroll
    for (int r = 0; r < 4; ++r) cst[q][r] = 0.f;

  uint4 zA[2], zB[2];
  {
    const int seq0 = dir ? 31 : 0;
    zA[0] = zb[(size_t)(seq0 << 2) * 512 + tid];
    zA[1] = zb[(size_t)((seq0 << 2) + 1) * 512 + tid];
  }

  for (int t = 0; t < 32; ++t) {
    const ushort* hprev = hbuf[(t + 1) & 1];
    ushort* hnext = hbuf[t & 1];

    if (t) {
      const int seqP = dir ? (32 - t) : (t - 1);
      const int row = tid >> 5, c4 = tid & 31;
      const uint4 v = *(const uint4*)((const char*)hprev + row * 512 +
                                      ((c4 ^ (row & 7)) << 4));
      const int n = rowbase + row, b = n >> 5, sp = n & 31;
      const int X = vert ? seqP : sp, Y = vert ? sp : seqP;
      *(uint4*)&outbuf[(((size_t)(b * 32 + X) * 32 + Y) << 9) + (dir << 8) +
                       (c4 << 3)] = v;
    }

#pragma unroll
    for (int q = 0; q < 2; ++q) {
      uint4(&zc)[2] = (q == 0) ? zA : zB;
      uint4(&zn)[2] = (q == 0) ? zB : zA;

      f32x4 acc[4];
#pragma unroll
      for (int g = 0; g < 4; ++g) {
        const unsigned int u0 = (g == 0) ? zc[0].x : (g == 1) ? zc[0].y
                                : (g == 2) ? zc[0].z : zc[0].w;
        const unsigned int u1 = (g == 0) ? zc[1].x : (g == 1) ? zc[1].y
                                : (g == 2) ? zc[1].z : zc[1].w;
        acc[g][0] = bf2f((ushort)(u0 & 0xffffu));
        acc[g][1] = bf2f((ushort)(u0 >> 16));
        acc[g][2] = bf2f((ushort)(u1 & 0xffffu));
        acc[g][3] = bf2f((ushort)(u1 >> 16));
      }

      if (t) {
        uint4 bfr[2][3];  // g=1..3 ring (g=0 from rres)
#pragma unroll
        for (int g = 1; g < 4; ++g)
          bfr[0][g - 1] =
              rFd[(size_t)(((g << 4) + (w << 1) + q) << 3) * 64 + lane];
#pragma unroll
        for (int kc = 0; kc < 8; ++kc) {
          const int cur = kc & 1;
          if (kc < 7) {
#pragma unroll
            for (int g = 1; g < 4; ++g)
              bfr[cur ^ 1][g - 1] =
                  rFd[((size_t)(((g << 4) + (w << 1) + q) << 3) + kc + 1) * 64 +
                      lane];
          }
          const int c4 = (kc << 2) + kg;
          const uint4 a = *(const uint4*)((const char*)hprev + l16 * 512 +
                                          ((c4 ^ (l16 & 7)) << 4));
          const bf16x8 ab = __builtin_bit_cast(bf16x8, a);
          const bf16x8 b0 = __builtin_bit_cast(
              bf16x8, rres[(size_t)(((((w << 1) + q) << 3) + kc) << 6) + lane]);
          acc[0] = mfma16(ab, b0, acc[0]);
#pragma unroll
          for (int g = 1; g < 4; ++g)
            acc[g] = mfma16(ab, __builtin_bit_cast(bf16x8, bfr[cur][g - 1]),
                            acc[g]);
        }
      }

      if (t < 31 || q == 0) {
        const int tn = q ? (t + 1) : t;
        const int qn = q ^ 1;
        const int seqn = dir ? (31 - tn) : tn;
        zn[0] = zb[(size_t)(((seqn << 1) + qn) << 1) * 512 + tid];
        zn[1] = zb[(size_t)((((seqn << 1) + qn) << 1) + 1) * 512 + tid];
      }

      const int col = (w << 5) + (q << 4) + l16;
#pragma unroll
      for (int r = 0; r < 4; ++r) {
        const float zi = acc[0][r];
        const float zf = acc[1][r];
        const float zg = acc[2][r];
        const float zo = acc[3][r];
        const float cn = sigm(zf) * cst[q][r] + sigm(zi) * tanh_(zg);
        cst[q][r] = cn;
        const float hv = sigm(zo) * tanh_(cn);
        const int row = (kg << 2) + r;
        *(ushort*)((char*)hnext + row * 512 +
                   (((col >> 3) ^ (row & 7)) << 4) + ((col & 7) << 1)) =
            f2bf(hv);
      }
    }
    __syncthreads();
  }

  {
    const int seqP = dir ? 0 : 31;
    const ushort* hl = hbuf[1];
    const int row = tid >> 5, c4 = tid & 31;
    const uint4 v = *(const uint4*)((const char*)hl + row * 512 +
                                    ((c4 ^ (row & 7)) << 4));
    const int n = rowbase + row, b = n >> 5, sp = n & 31;
    const int X = vert ? seqP : sp, Y = vert ? sp : seqP;
    *(uint4*)&outbuf[(((size_t)(b * 32 + X) * 32 + Y) << 9) + (dir << 8) +
                     (c4 << 3)] = v;
  }
}

// --------------------------------------------------------------------------
// Dual-dir horizontal projection, 8-wave, BK=64, DOUBLE-BUFFERED staging:
// stage(t+1) issued before MFMA(t); one __syncthreads per K-iter (8 total).
__global__ __launch_bounds__(512) void gemm_bt_dual(
    const ushort* __restrict__ A, const ushort* __restrict__ BT0,
    const ushort* __restrict__ BT1, const float* __restrict__ bias0,
    const float* __restrict__ bias1, uint4* __restrict__ Zf) {
  const int tid = threadIdx.x;
  const int lane = tid & 63, wid = tid >> 6;
  const int l16 = lane & 15, kg = lane >> 4;
  const int wr = wid >> 1, wc = wid & 1;  // 4m x 2n
  const int bid = blockIdx.x;
  const int xcd = bid & 7, lid = bid >> 3;
  const int m0 = ((xcd << 6) + (lid >> 4)) << 7;
  const int nb = lid & 15;
  const int dirq = nb >> 3;
  const int hc0 = (nb & 7) << 5;
  const ushort* BT = dirq ? BT1 : BT0;
  const float* bias = dirq ? bias1 : bias0;
  uint4* Cz = Zf + (size_t)dirq * 8388608;

  union SM {
    struct { uint4 A[2][128][8]; uint4 B[2][128][8]; } k;  // 64 KB
    ushort eh[128][136];
  };
  __shared__ SM sm;

  f32x4 acc[2][4];
#pragma unroll
  for (int mt = 0; mt < 2; ++mt)
#pragma unroll
    for (int nt = 0; nt < 4; ++nt) acc[mt][nt] = (f32x4){0.f, 0.f, 0.f, 0.f};

  auto STAGE = [&](int k0, int bi) {
#pragma unroll
    for (int c = 0; c < 2; ++c) {
      const int cid = (wid << 7) + (c << 6) + lane;  // 0..1023
      const int row = cid >> 3, ch = cid & 7;
      const int sch = ch ^ (row & 7);
      const int brow = ((row >> 5) << 8) + hc0 + (row & 31);
      load_lds16(A + (size_t)(m0 + row) * 512 + k0 + (sch << 3),
                 (uint4*)sm.k.A[bi] + (cid - lane));
      load_lds16(BT + (size_t)brow * 512 + k0 + (sch << 3),
                 (uint4*)sm.k.B[bi] + (cid - lane));
    }
  };

  STAGE(0, 0);
  __syncthreads();  // drains stage(0)

  for (int t = 0; t < 8; ++t) {
    const int bi = t & 1;
    if (t < 7) STAGE((t + 1) << 6, bi ^ 1);  // flies under MFMA(t)
#pragma unroll
    for (int kk = 0; kk < 2; ++kk) {
      const int q = (kk << 2) + kg;
      bf16x8 a[2], b[4];
#pragma unroll
      for (int mt = 0; mt < 2; ++mt) {
        const int rr = (wr << 5) + (mt << 4) + l16;
        a[mt] = __builtin_bit_cast(bf16x8, sm.k.A[bi][rr][q ^ (rr & 7)]);
      }
#pragma unroll
      for (int nt = 0; nt < 4; ++nt) {
        const int rr = (wc << 6) + (nt << 4) + l16;
        b[nt] = __builtin_bit_cast(bf16x8, sm.k.B[bi][rr][q ^ (rr & 7)]);
      }
#pragma unroll
      for (int mt = 0; mt < 2; ++mt)
#pragma unroll
        for (int nt = 0; nt < 4; ++nt)
          acc[mt][nt] = mfma16(a[mt], b[nt], acc[mt][nt]);
    }
    __syncthreads();  // drains stage(t+1); closes reads of buf bi
  }

  float bn[4];
#pragma unroll
  for (int nt = 0; nt < 4; ++nt) {
    const int lcol = (wc << 6) + (nt << 4) + l16;
    bn[nt] = bias[((lcol >> 5) << 8) + hc0 + (lcol & 31)];
  }

#pragma unroll
  for (int mt = 0; mt < 2; ++mt) {
#pragma unroll
    for (int nt = 0; nt < 4; ++nt) {
      const int col = (wc << 6) + (nt << 4) + l16;
#pragma unroll
      for (int r = 0; r < 4; ++r) {
        const int rowl = (wr << 5) + (mt << 4) + (kg << 2) + r;
        sm.eh[rowl][col] = f2bf(acc[mt][nt][r] + bn[nt]);
      }
    }
  }
  __syncthreads();

#pragma unroll
  for (int h = 0; h < 2; ++h) {
    const int n_a = ((m0 >> 6) + h) << 1;
    const int rbz = n_a >> 4;
    const int n2l = (n_a & 15) >> 1;
    const int kgz = n2l >> 1, pz = n2l & 1;
#pragma unroll
    for (int it = 0; it < 2; ++it) {
      const int e = tid + (it << 9);
      const int seq = e >> 5, hl = e & 31;
      const int qv = hl >> 4, l16v = hl & 15;
      const int wz = (hc0 + hl) >> 5;
      const int tidz = (wz << 6) + (kgz << 4) + l16v;
      uint4 o;
      o.x = (unsigned int)sm.eh[(h << 6) + seq][hl] |
            ((unsigned int)sm.eh[(h << 6) + 32 + seq][hl] << 16);
      o.y = (unsigned int)sm.eh[(h << 6) + seq][32 + hl] |
            ((unsigned int)sm.eh[(h << 6) + 32 + seq][32 + hl] << 16);
      o.z = (unsigned int)sm.eh[(h << 6) + seq][64 + hl] |
            ((unsigned int)sm.eh[(h << 6) + 32 + seq][64 + hl] << 16);
      o.w = (unsigned int)sm.eh[(h << 6) + seq][96 + hl] |
            ((unsigned int)sm.eh[(h << 6) + 32 + seq][96 + hl] << 16);
      Cz[(size_t)rbz * 65536 + (size_t)((((seq << 1) + qv) << 1) + pz) * 512 +
         tidz] = o;
    }
  }
}

// --------------------------------------------------------------------------
// Dense, 8-wave, BK=64, double-buffered staging: out = relu(A @ WdT^T + bd).
__global__ __launch_bounds__(512) void gemm_dense(
    const ushort* __restrict__ A, const ushort* __restrict__ BT,
    const float* __restrict__ bias, float* __restrict__ out) {
  const int tid = threadIdx.x;
  const int lane = tid & 63, wid = tid >> 6;
  const int l16 = lane & 15, kg = lane >> 4;
  const int wr = wid >> 1, wc = wid & 1;
  const int bid = blockIdx.x;
  const int xcd = bid & 7, lid = bid >> 3;
  const int m0 = ((xcd << 6) + (lid >> 3)) << 7;
  const int n0 = (lid & 7) << 7;

  union SM {
    struct { uint4 A[2][128][8]; uint4 B[2][128][8]; } k;  // 64 KB
    float ef[64][132];
  };
  __shared__ SM sm;

  f32x4 acc[2][4];
#pragma unroll
  for (int mt = 0; mt < 2; ++mt)
#pragma unroll
    for (int nt = 0; nt < 4; ++nt) acc[mt][nt] = (f32x4){0.f, 0.f, 0.f, 0.f};

  auto STAGE = [&](int k0, int bi) {
#pragma unroll
    for (int c = 0; c < 2; ++c) {
      const int cid = (wid << 7) + (c << 6) + lane;
      const int row = cid >> 3, ch = cid & 7;
      const int sch = ch ^ (row & 7);
      load_lds16(A + (size_t)(m0 + row) * 512 + k0 + (sch << 3),
                 (uint4*)sm.k.A[bi] + (cid - lane));
      load_lds16(BT + (size_t)(n0 + row) * 512 + k0 + (sch << 3),
                 (uint4*)sm.k.B[bi] + (cid - lane));
    }
  };

  STAGE(0, 0);
  __syncthreads();

  for (int t = 0; t < 8; ++t) {
    const int bi = t & 1;
    if (t < 7) STAGE((t + 1) << 6, bi ^ 1);
#pragma unroll
    for (int kk = 0; kk < 2; ++kk) {
      const int q = (kk << 2) + kg;
      bf16x8 a[2], b[4];
#pragma unroll
      for (int mt = 0; mt < 2; ++mt) {
        const int rr = (wr << 5) + (mt << 4) + l16;
        a[mt] = __builtin_bit_cast(bf16x8, sm.k.A[bi][rr][q ^ (rr & 7)]);
      }
#pragma unroll
      for (int nt = 0; nt < 4; ++nt) {
        const int rr = (wc << 6) + (nt << 4) + l16;
        b[nt] = __builtin_bit_cast(bf16x8, sm.k.B[bi][rr][q ^ (rr & 7)]);
      }
#pragma unroll
      for (int mt = 0; mt < 2; ++mt)
#pragma unroll
        for (int nt = 0; nt < 4; ++nt)
          acc[mt][nt] = mfma16(a[mt], b[nt], acc[mt][nt]);
    }
    __syncthreads();
  }

  float bn[4];
#pragma unroll
  for (int nt = 0; nt < 4; ++nt)
    bn[nt] = bias[n0 + (wc << 6) + (nt << 4) + l16];

#pragma unroll
  for (int h = 0; h < 2; ++h) {
    __syncthreads();
    if ((wr >> 1) == h) {
#pragma unroll
      for (int mt = 0; mt < 2; ++mt) {
#pragma unroll
        for (int nt = 0; nt < 4; ++nt) {
          const int col = (wc << 6) + (nt << 4) + l16;
#pragma unroll
          for (int r = 0; r < 4; ++r) {
            const int rowl = ((wr & 1) << 5) + (mt << 4) + (kg << 2) + r;
            sm.ef[rowl][col] = fmaxf(acc[mt][nt][r] + bn[nt], 0.f);
          }
        }
      }
    }
    __syncthreads();
#pragma unroll
    for (int it = 0; it < 4; ++it) {
      const int c = tid + (it << 9);
      const int row = c >> 5, co = (c & 31) << 2;
      const f32x4 v = *(const f32x4*)&sm.ef[row][co];
      __builtin_nontemporal_store(
          v, (f32x4*)(out + (size_t)(m0 + (h << 6) + row) * 1024 + n0 + co));
    }
  }
}

}  // namespace

extern "C" void kernel_launch(void* const* d_in, const int* in_sizes, int n_in,
                              void* d_out, int out_size, void* d_ws, size_t ws_size,
                              hipStream_t stream) {
  (void)in_sizes; (void)n_in; (void)out_size; (void)ws_size;
  const float* x    = (const float*)d_in[0];
  const float* k_ud = (const float*)d_in[1];
  const float* r_ud = (const float*)d_in[2];
  const float* b_ud = (const float*)d_in[3];
  const float* k_du = (const float*)d_in[4];
  const float* r_du = (const float*)d_in[5];
  const float* b_du = (const float*)d_in[6];
  const float* k_lr = (const float*)d_in[7];
  const float* r_lr = (const float*)d_in[8];
  const float* b_lr = (const float*)d_in[9];
  const float* k_rl = (const float*)d_in[10];
  const float* r_rl = (const float*)d_in[11];
  const float* b_rl = (const float*)d_in[12];
  const float* Wd   = (const float*)d_in[13];
  const float* bd   = (const float*)d_in[14];

  ushort* W     = (ushort*)d_ws;
  ushort* Z     = W;                      // Zf: 268 MB
  ushort* vbuf  = Z + 134217728;          // 33554432
  ushort* rF    = vbuf + 33554432;        // 1048576
  ushort* kTh   = rF + 1048576;           // 1048576
  ushort* WdT   = kTh + 1048576;          // 524288
  ushort* kfragV = WdT + 524288;          // 65536
  uint4* Zf = (uint4*)Z;

  // ---- weight prep ----
  rfrag_all<<<dim3(128, 4), 256, 0, stream>>>(r_ud, r_du, r_lr, r_rl, rF);
  transpose_all<<<dim3(2048, 3), 256, 0, stream>>>(k_lr, k_rl, Wd, kTh,
                                                   kTh + 524288, WdT);
  kfragv_kernel<<<dim3(16, 2), 256, 0, stream>>>(k_ud, b_ud, k_du, b_du,
                                                 kfragV);

  // ---- vertical sweep (zx in-kernel) ----
  lstm_sweepV<<<dim3(128, 2), 512, 0, stream>>>(x, kfragV, (const uint4*)rF,
                                                vbuf);

  // ---- horizontal input projection (both dirs, dbuf) ----
  gemm_bt_dual<<<8192, 512, 0, stream>>>(vbuf, kTh, kTh + 524288, b_lr, b_rl,
                                         Zf);

  // ---- horizontal sweep (g0 R-resident) ----
  lstm_sweep7<<<dim3(128, 2), 512, 0, stream>>>(
      Zf, (const uint4*)(rF + 524288), vbuf, 0);

  // ---- dense + relu (dbuf) ----
  gemm_dense<<<4096, 512, 0, stream>>>(vbuf, WdT, bd, (float*)d_out);
}